// Round 1
// baseline (176.170 us; speedup 1.0000x reference)
//
#include <hip/hip_runtime.h>

#define GD 64
#define GVOX (GD * GD * GD)

// ---------------------------------------------------------------------------
// Repack grid [3][64][64][64] -> channels-last float4[64^3] (w component = 0).
// One corner fetch becomes a single 16B load carrying all 3 channels.
// ---------------------------------------------------------------------------
__global__ __launch_bounds__(256) void repack_grid(const float* __restrict__ g,
                                                   float4* __restrict__ gt) {
    int v = blockIdx.x * 256 + threadIdx.x;
    if (v < GVOX) {
        float4 o;
        o.x = g[v];
        o.y = g[v + GVOX];
        o.z = g[v + 2 * GVOX];
        o.w = 0.f;
        gt[v] = o;
    }
}

// ---------------------------------------------------------------------------
// Per-point trilinear sample from channels-last grid, accumulated into the
// point coordinates (residual add). Branchless zeros-padding: clamp indices,
// zero the weight of invalid corners.
// ---------------------------------------------------------------------------
__device__ __forceinline__ void samp_add(const float4* __restrict__ gt,
                                         float& px, float& py, float& pz) {
    // ix = ((x+1)*64 - 1) * 0.5 = 32*x + 31.5
    float ix = fmaf(px, 32.f, 31.5f);
    float iy = fmaf(py, 32.f, 31.5f);
    float iz = fmaf(pz, 32.f, 31.5f);
    float fx = floorf(ix), fy = floorf(iy), fz = floorf(iz);
    float tx = ix - fx, ty = iy - fy, tz = iz - fz;
    int x0 = (int)fx, y0 = (int)fy, z0 = (int)fz;

    int xi0 = max(x0, 0), xi1 = min(x0 + 1, GD - 1);
    int yi0 = max(y0, 0), yi1 = min(y0 + 1, GD - 1);
    int zi0 = max(z0, 0), zi1 = min(z0 + 1, GD - 1);

    float wx0 = (1.f - tx) * (x0 >= 0 ? 1.f : 0.f);
    float wx1 = tx * (x0 < GD - 1 ? 1.f : 0.f);
    float wy0 = (1.f - ty) * (y0 >= 0 ? 1.f : 0.f);
    float wy1 = ty * (y0 < GD - 1 ? 1.f : 0.f);
    float wz0 = (1.f - tz) * (z0 >= 0 ? 1.f : 0.f);
    float wz1 = tz * (z0 < GD - 1 ? 1.f : 0.f);

    int zb0 = zi0 << 12, zb1 = zi1 << 12;
    int yb0 = yi0 << 6, yb1 = yi1 << 6;

    float wz0y0 = wz0 * wy0, wz0y1 = wz0 * wy1;
    float wz1y0 = wz1 * wy0, wz1y1 = wz1 * wy1;

    float a0 = 0.f, a1 = 0.f, a2 = 0.f;
#define CORNER(zb, yb, xi, w)                                  \
    {                                                          \
        float4 g4 = gt[(zb) + (yb) + (xi)];                    \
        a0 = fmaf((w), g4.x, a0);                              \
        a1 = fmaf((w), g4.y, a1);                              \
        a2 = fmaf((w), g4.z, a2);                              \
    }
    CORNER(zb0, yb0, xi0, wz0y0 * wx0);
    CORNER(zb0, yb0, xi1, wz0y0 * wx1);
    CORNER(zb0, yb1, xi0, wz0y1 * wx0);
    CORNER(zb0, yb1, xi1, wz0y1 * wx1);
    CORNER(zb1, yb0, xi0, wz1y0 * wx0);
    CORNER(zb1, yb0, xi1, wz1y0 * wx1);
    CORNER(zb1, yb1, xi0, wz1y1 * wx0);
    CORNER(zb1, yb1, xi1, wz1y1 * wx1);
#undef CORNER
    px += a0;
    py += a1;
    pz += a2;
}

// Direct-layout variant (fallback when d_ws is too small): 3 plane loads/corner.
__device__ __forceinline__ void samp_add_direct(const float* __restrict__ g,
                                                float& px, float& py, float& pz) {
    float ix = fmaf(px, 32.f, 31.5f);
    float iy = fmaf(py, 32.f, 31.5f);
    float iz = fmaf(pz, 32.f, 31.5f);
    float fx = floorf(ix), fy = floorf(iy), fz = floorf(iz);
    float tx = ix - fx, ty = iy - fy, tz = iz - fz;
    int x0 = (int)fx, y0 = (int)fy, z0 = (int)fz;
    int xi0 = max(x0, 0), xi1 = min(x0 + 1, GD - 1);
    int yi0 = max(y0, 0), yi1 = min(y0 + 1, GD - 1);
    int zi0 = max(z0, 0), zi1 = min(z0 + 1, GD - 1);
    float wx0 = (1.f - tx) * (x0 >= 0 ? 1.f : 0.f);
    float wx1 = tx * (x0 < GD - 1 ? 1.f : 0.f);
    float wy0 = (1.f - ty) * (y0 >= 0 ? 1.f : 0.f);
    float wy1 = ty * (y0 < GD - 1 ? 1.f : 0.f);
    float wz0 = (1.f - tz) * (z0 >= 0 ? 1.f : 0.f);
    float wz1 = tz * (z0 < GD - 1 ? 1.f : 0.f);
    int zb0 = zi0 << 12, zb1 = zi1 << 12;
    int yb0 = yi0 << 6, yb1 = yi1 << 6;
    float wz0y0 = wz0 * wy0, wz0y1 = wz0 * wy1;
    float wz1y0 = wz1 * wy0, wz1y1 = wz1 * wy1;
    float a0 = 0.f, a1 = 0.f, a2 = 0.f;
#define CORNERD(zb, yb, xi, w)                                 \
    {                                                          \
        int idx = (zb) + (yb) + (xi);                          \
        a0 = fmaf((w), g[idx], a0);                            \
        a1 = fmaf((w), g[idx + GVOX], a1);                     \
        a2 = fmaf((w), g[idx + 2 * GVOX], a2);                 \
    }
    CORNERD(zb0, yb0, xi0, wz0y0 * wx0);
    CORNERD(zb0, yb0, xi1, wz0y0 * wx1);
    CORNERD(zb0, yb1, xi0, wz0y1 * wx0);
    CORNERD(zb0, yb1, xi1, wz0y1 * wx1);
    CORNERD(zb1, yb0, xi0, wz1y0 * wx0);
    CORNERD(zb1, yb0, xi1, wz1y0 * wx1);
    CORNERD(zb1, yb1, xi0, wz1y1 * wx0);
    CORNERD(zb1, yb1, xi1, wz1y1 * wx1);
#undef CORNERD
    px += a0;
    py += a1;
    pz += a2;
}

// ---------------------------------------------------------------------------
// Main kernel: 4 points per thread -> 3 aligned float4 loads + 3 float4 stores.
// ---------------------------------------------------------------------------
__global__ __launch_bounds__(256) void sample4(const float4* __restrict__ pts,
                                               const float4* __restrict__ gt,
                                               float4* __restrict__ out,
                                               int nthreads) {
    int t = blockIdx.x * 256 + threadIdx.x;
    if (t >= nthreads) return;
    float4 a = pts[t * 3 + 0];
    float4 b = pts[t * 3 + 1];
    float4 c = pts[t * 3 + 2];
    samp_add(gt, a.x, a.y, a.z);
    samp_add(gt, a.w, b.x, b.y);
    samp_add(gt, b.z, b.w, c.x);
    samp_add(gt, c.y, c.z, c.w);
    out[t * 3 + 0] = a;
    out[t * 3 + 1] = b;
    out[t * 3 + 2] = c;
}

__global__ __launch_bounds__(256) void sample4_direct(const float4* __restrict__ pts,
                                                      const float* __restrict__ g,
                                                      float4* __restrict__ out,
                                                      int nthreads) {
    int t = blockIdx.x * 256 + threadIdx.x;
    if (t >= nthreads) return;
    float4 a = pts[t * 3 + 0];
    float4 b = pts[t * 3 + 1];
    float4 c = pts[t * 3 + 2];
    samp_add_direct(g, a.x, a.y, a.z);
    samp_add_direct(g, a.w, b.x, b.y);
    samp_add_direct(g, b.z, b.w, c.x);
    samp_add_direct(g, c.y, c.z, c.w);
    out[t * 3 + 0] = a;
    out[t * 3 + 1] = b;
    out[t * 3 + 2] = c;
}

// Scalar tail kernel (handles npts % 4 remainder; with the given sizes rem==0).
__global__ __launch_bounds__(64) void sample_tail(const float* __restrict__ pts,
                                                  const float* __restrict__ g,
                                                  float* __restrict__ out,
                                                  int start, int npts) {
    int i = start + blockIdx.x * 64 + threadIdx.x;
    if (i >= npts) return;
    float x = pts[i * 3 + 0], y = pts[i * 3 + 1], z = pts[i * 3 + 2];
    samp_add_direct(g, x, y, z);
    out[i * 3 + 0] = x;
    out[i * 3 + 1] = y;
    out[i * 3 + 2] = z;
}

extern "C" void kernel_launch(void* const* d_in, const int* in_sizes, int n_in,
                              void* d_out, int out_size, void* d_ws, size_t ws_size,
                              hipStream_t stream) {
    const float* pts = (const float*)d_in[0];     // [B, N, 3] fp32
    const float* grid = (const float*)d_in[1];    // [3, 64, 64, 64] fp32
    float* out = (float*)d_out;

    int total_f = in_sizes[0];      // B*N*3
    int npts = total_f / 3;
    int nthreads = npts / 4;        // 4 points per thread
    int rem = npts - nthreads * 4;

    bool use_ws = ws_size >= (size_t)GVOX * 16;

    if (use_ws) {
        repack_grid<<<(GVOX + 255) / 256, 256, 0, stream>>>(grid, (float4*)d_ws);
        sample4<<<(nthreads + 255) / 256, 256, 0, stream>>>(
            (const float4*)pts, (const float4*)d_ws, (float4*)out, nthreads);
    } else {
        sample4_direct<<<(nthreads + 255) / 256, 256, 0, stream>>>(
            (const float4*)pts, grid, (float4*)out, nthreads);
    }
    if (rem > 0) {
        sample_tail<<<(rem + 63) / 64, 64, 0, stream>>>(pts, grid, out,
                                                        nthreads * 4, npts);
    }
}

// Round 2
// 100.150 us; speedup vs baseline: 1.7591x; 1.7591x over previous
//
#include <hip/hip_runtime.h>
#include <hip/hip_fp16.h>

#define GD 64
#define GVOX (GD * GD * GD)

typedef float vfloat4 __attribute__((ext_vector_type(4)));

// Pair-packed fp16 grid entry at (z,y,x):
//   a = {v[x].c0, v[x].c1}, b = {v[x].c2, 0}, c = {v[x1].c0, v[x1].c1}, d = {v[x1].c2, 0}
// where x1 = min(x+1, 63). One 16B gather fetches BOTH x-corners, all channels.
struct alignas(16) Half8 {
    __half2 a, b, c, d;
};

// ---------------------------------------------------------------------------
// Repack [3][64][64][64] fp32 -> Half8[64^3] (4 MB) in d_ws.
// ---------------------------------------------------------------------------
__global__ __launch_bounds__(256) void repack_pairs(const float* __restrict__ g,
                                                    Half8* __restrict__ pg) {
    int v = blockIdx.x * 256 + threadIdx.x;
    if (v >= GVOX) return;
    int x = v & (GD - 1);
    int v1 = v + (x < GD - 1 ? 1 : 0);
    Half8 o;
    o.a = __floats2half2_rn(g[v], g[v + GVOX]);
    o.b = __floats2half2_rn(g[v + 2 * GVOX], 0.f);
    o.c = __floats2half2_rn(g[v1], g[v1 + GVOX]);
    o.d = __floats2half2_rn(g[v1 + 2 * GVOX], 0.f);
    pg[v] = o;
}

// ---------------------------------------------------------------------------
// Trilinear sample (zeros padding, align_corners=False) + residual add.
// 4 pair-gathers per point. Branchless borders: clamp indices, zero weights.
// ---------------------------------------------------------------------------
__device__ __forceinline__ void samp_pair(const Half8* __restrict__ pg,
                                          float& px, float& py, float& pz) {
    // ix = ((x+1)*64 - 1) * 0.5 = 32*x + 31.5; pts in [-1,1] -> ix in [-0.5, 63.5]
    float ix = fmaf(px, 32.f, 31.5f);
    float iy = fmaf(py, 32.f, 31.5f);
    float iz = fmaf(pz, 32.f, 31.5f);
    float fx = floorf(ix), fy = floorf(iy), fz = floorf(iz);
    float tx = ix - fx, ty = iy - fy, tz = iz - fz;
    int x0 = (int)fx, y0 = (int)fy, z0 = (int)fz;

    int xp = min(max(x0, 0), GD - 1);
    int yi0 = max(y0, 0), yi1 = min(y0 + 1, GD - 1);
    int zi0 = max(z0, 0), zi1 = min(z0 + 1, GD - 1);

    float wx0 = (1.f - tx) * (x0 >= 0 ? 1.f : 0.f);
    float wx1 = tx * (x0 < GD - 1 ? 1.f : 0.f);
    float wy0 = (1.f - ty) * (y0 >= 0 ? 1.f : 0.f);
    float wy1 = ty * (y0 < GD - 1 ? 1.f : 0.f);
    float wz0 = (1.f - tz) * (z0 >= 0 ? 1.f : 0.f);
    float wz1 = tz * (z0 < GD - 1 ? 1.f : 0.f);

    // x0 == -1: pair at xp=0 holds (v[0], v[1]); needed x1-corner is v[0] = pair.lo.
    bool lo = (x0 < 0);

    int zb0 = zi0 << 12, zb1 = zi1 << 12;
    int yb0 = yi0 << 6, yb1 = yi1 << 6;

    float wz0y0 = wz0 * wy0, wz0y1 = wz0 * wy1;
    float wz1y0 = wz1 * wy0, wz1y1 = wz1 * wy1;

    float a0 = 0.f, a1 = 0.f, a2 = 0.f;
#define G4(zb, yb, wzy)                                          \
    {                                                            \
        Half8 p = pg[(zb) + (yb) + xp];                          \
        float2 A = __half22float2(p.a);                          \
        float Bx = __low2float(p.b);                             \
        float2 C = __half22float2(p.c);                          \
        float Dx = __low2float(p.d);                             \
        float c1x = lo ? A.x : C.x;                              \
        float c1y = lo ? A.y : C.y;                              \
        float c1z = lo ? Bx : Dx;                                \
        float e0 = (wzy) * wx0, e1 = (wzy) * wx1;                \
        a0 = fmaf(e0, A.x, a0);                                  \
        a0 = fmaf(e1, c1x, a0);                                  \
        a1 = fmaf(e0, A.y, a1);                                  \
        a1 = fmaf(e1, c1y, a1);                                  \
        a2 = fmaf(e0, Bx, a2);                                   \
        a2 = fmaf(e1, c1z, a2);                                  \
    }
    G4(zb0, yb0, wz0y0);
    G4(zb0, yb1, wz0y1);
    G4(zb1, yb0, wz1y0);
    G4(zb1, yb1, wz1y1);
#undef G4
    px += a0;
    py += a1;
    pz += a2;
}

// ---------------------------------------------------------------------------
// Main kernel. Block = 256 threads = 1024 points = 768 float4.
// Coalesced nontemporal global I/O + LDS transpose to per-thread AoS.
// ---------------------------------------------------------------------------
__global__ __launch_bounds__(256) void sample_lds(const vfloat4* __restrict__ pts,
                                                  const Half8* __restrict__ pg,
                                                  vfloat4* __restrict__ out,
                                                  int nf4) {
    __shared__ vfloat4 lds[768];
    int tid = threadIdx.x;
    int base = blockIdx.x * 768;

    vfloat4 v0 = {0.f, 0.f, 0.f, 0.f};
    vfloat4 v1 = {0.f, 0.f, 0.f, 0.f};
    vfloat4 v2 = {0.f, 0.f, 0.f, 0.f};
    if (base + tid < nf4) v0 = __builtin_nontemporal_load(&pts[base + tid]);
    if (base + 256 + tid < nf4) v1 = __builtin_nontemporal_load(&pts[base + 256 + tid]);
    if (base + 512 + tid < nf4) v2 = __builtin_nontemporal_load(&pts[base + 512 + tid]);
    lds[tid] = v0;
    lds[tid + 256] = v1;
    lds[tid + 512] = v2;
    __syncthreads();

    vfloat4 a = lds[tid * 3 + 0];
    vfloat4 b = lds[tid * 3 + 1];
    vfloat4 c = lds[tid * 3 + 2];

    float f[12] = {a.x, a.y, a.z, a.w, b.x, b.y, b.z, b.w, c.x, c.y, c.z, c.w};
    samp_pair(pg, f[0], f[1], f[2]);
    samp_pair(pg, f[3], f[4], f[5]);
    samp_pair(pg, f[6], f[7], f[8]);
    samp_pair(pg, f[9], f[10], f[11]);
    a = (vfloat4){f[0], f[1], f[2], f[3]};
    b = (vfloat4){f[4], f[5], f[6], f[7]};
    c = (vfloat4){f[8], f[9], f[10], f[11]};

    __syncthreads();
    lds[tid * 3 + 0] = a;
    lds[tid * 3 + 1] = b;
    lds[tid * 3 + 2] = c;
    __syncthreads();

    if (base + tid < nf4) __builtin_nontemporal_store(lds[tid], &out[base + tid]);
    if (base + 256 + tid < nf4)
        __builtin_nontemporal_store(lds[tid + 256], &out[base + 256 + tid]);
    if (base + 512 + tid < nf4)
        __builtin_nontemporal_store(lds[tid + 512], &out[base + 512 + tid]);
}

// ---------------------------------------------------------------------------
// Fallback (ws too small): direct 3-plane gather, round-1 style.
// ---------------------------------------------------------------------------
__device__ __forceinline__ void samp_add_direct(const float* __restrict__ g,
                                                float& px, float& py, float& pz) {
    float ix = fmaf(px, 32.f, 31.5f);
    float iy = fmaf(py, 32.f, 31.5f);
    float iz = fmaf(pz, 32.f, 31.5f);
    float fx = floorf(ix), fy = floorf(iy), fz = floorf(iz);
    float tx = ix - fx, ty = iy - fy, tz = iz - fz;
    int x0 = (int)fx, y0 = (int)fy, z0 = (int)fz;
    int xi0 = max(x0, 0), xi1 = min(x0 + 1, GD - 1);
    int yi0 = max(y0, 0), yi1 = min(y0 + 1, GD - 1);
    int zi0 = max(z0, 0), zi1 = min(z0 + 1, GD - 1);
    float wx0 = (1.f - tx) * (x0 >= 0 ? 1.f : 0.f);
    float wx1 = tx * (x0 < GD - 1 ? 1.f : 0.f);
    float wy0 = (1.f - ty) * (y0 >= 0 ? 1.f : 0.f);
    float wy1 = ty * (y0 < GD - 1 ? 1.f : 0.f);
    float wz0 = (1.f - tz) * (z0 >= 0 ? 1.f : 0.f);
    float wz1 = tz * (z0 < GD - 1 ? 1.f : 0.f);
    int zb0 = zi0 << 12, zb1 = zi1 << 12;
    int yb0 = yi0 << 6, yb1 = yi1 << 6;
    float wz0y0 = wz0 * wy0, wz0y1 = wz0 * wy1;
    float wz1y0 = wz1 * wy0, wz1y1 = wz1 * wy1;
    float s0 = 0.f, s1 = 0.f, s2 = 0.f;
#define CORNERD(zb, yb, xi, w)                   \
    {                                            \
        int idx = (zb) + (yb) + (xi);            \
        s0 = fmaf((w), g[idx], s0);              \
        s1 = fmaf((w), g[idx + GVOX], s1);       \
        s2 = fmaf((w), g[idx + 2 * GVOX], s2);   \
    }
    CORNERD(zb0, yb0, xi0, wz0y0 * wx0);
    CORNERD(zb0, yb0, xi1, wz0y0 * wx1);
    CORNERD(zb0, yb1, xi0, wz0y1 * wx0);
    CORNERD(zb0, yb1, xi1, wz0y1 * wx1);
    CORNERD(zb1, yb0, xi0, wz1y0 * wx0);
    CORNERD(zb1, yb0, xi1, wz1y0 * wx1);
    CORNERD(zb1, yb1, xi0, wz1y0 * wx0 * 0.f + wz1y1 * wx0);
    CORNERD(zb1, yb1, xi1, wz1y1 * wx1);
#undef CORNERD
    px += s0;
    py += s1;
    pz += s2;
}

__global__ __launch_bounds__(256) void sample_direct(const float* __restrict__ pts,
                                                     const float* __restrict__ g,
                                                     float* __restrict__ out, int npts) {
    int i = blockIdx.x * 256 + threadIdx.x;
    if (i >= npts) return;
    float x = pts[i * 3 + 0], y = pts[i * 3 + 1], z = pts[i * 3 + 2];
    samp_add_direct(g, x, y, z);
    out[i * 3 + 0] = x;
    out[i * 3 + 1] = y;
    out[i * 3 + 2] = z;
}

extern "C" void kernel_launch(void* const* d_in, const int* in_sizes, int n_in,
                              void* d_out, int out_size, void* d_ws, size_t ws_size,
                              hipStream_t stream) {
    const float* pts = (const float*)d_in[0];   // [B, N, 3] fp32
    const float* grid = (const float*)d_in[1];  // [3, 64, 64, 64] fp32

    int total_f = in_sizes[0];  // B*N*3
    int npts = total_f / 3;

    if (ws_size >= (size_t)GVOX * sizeof(Half8) && (total_f % 4) == 0) {
        Half8* pg = (Half8*)d_ws;
        repack_pairs<<<(GVOX + 255) / 256, 256, 0, stream>>>(grid, pg);
        int nf4 = total_f / 4;                  // float4 count
        int nblocks = (nf4 + 767) / 768;        // 768 float4 (1024 points) per block
        sample_lds<<<nblocks, 256, 0, stream>>>((const vfloat4*)pts, pg,
                                                (vfloat4*)d_out, nf4);
    } else {
        sample_direct<<<(npts + 255) / 256, 256, 0, stream>>>(pts, grid,
                                                              (float*)d_out, npts);
    }
}

// Round 3
// 94.295 us; speedup vs baseline: 1.8683x; 1.0621x over previous
//
#include <hip/hip_runtime.h>

#define GD 64
#define GVOX (GD * GD * GD)

typedef float vfloat4 __attribute__((ext_vector_type(4)));
typedef _Float16 h8 __attribute__((ext_vector_type(8)));

// ---------------------------------------------------------------------------
// Brick-tiled, x-pair-packed fp16 grid (4 MB in d_ws).
// Entry (z,y,x): channels of voxel (z,y,x) and (z,y,min(x+1,63)) as 8 fp16.
// Entries are tiled so one 128B cache line holds a (4z x 2y x 1x) brick:
//   E = (z>>2)<<14 | (y>>1)<<9 | x<<3 | (z&3)<<1 | (y&1)
// A point's 4 needed entries ({z0,z1} x {y0,y1}, same x) touch on average
// 1.875 lines instead of 4.
// ---------------------------------------------------------------------------
__global__ __launch_bounds__(256) void repack_bricks(const float* __restrict__ g,
                                                     h8* __restrict__ pg) {
    int t = blockIdx.x * 256 + threadIdx.x;
    if (t >= GVOX) return;
    int eo = t & 7;
    int x = (t >> 3) & 63;
    int by = (t >> 9) & 31;
    int bz = t >> 14;
    int z = (bz << 2) | (eo >> 1);
    int y = (by << 1) | (eo & 1);
    int v = (z << 12) | (y << 6) | x;
    int v1 = v + (x < GD - 1 ? 1 : 0);
    h8 o;
    o[0] = (_Float16)g[v];
    o[1] = (_Float16)g[v + GVOX];
    o[2] = (_Float16)g[v + 2 * GVOX];
    o[3] = (_Float16)0.f;
    o[4] = (_Float16)g[v1];
    o[5] = (_Float16)g[v1 + GVOX];
    o[6] = (_Float16)g[v1 + 2 * GVOX];
    o[7] = (_Float16)0.f;
    pg[t] = o;   // coalesced: consecutive t -> consecutive 16B
}

// ---------------------------------------------------------------------------
// Phase A: per-point address + weight computation (no loads).
// ---------------------------------------------------------------------------
__device__ __forceinline__ void prep_point(float px, float py, float pz,
                                           int* __restrict__ e, float* __restrict__ w,
                                           float& cA, float& cC) {
    // ix = ((x+1)*64 - 1) * 0.5 = 32*x + 31.5
    float ix = fmaf(px, 32.f, 31.5f);
    float iy = fmaf(py, 32.f, 31.5f);
    float iz = fmaf(pz, 32.f, 31.5f);
    float fx = floorf(ix), fy = floorf(iy), fz = floorf(iz);
    float tx = ix - fx, ty = iy - fy, tz = iz - fz;
    int x0 = (int)fx, y0 = (int)fy, z0 = (int)fz;

    int xp = min(max(x0, 0), GD - 1);
    int yi0 = max(y0, 0), yi1 = min(y0 + 1, GD - 1);
    int zi0 = max(z0, 0), zi1 = min(z0 + 1, GD - 1);

    float wx0 = (1.f - tx) * (x0 >= 0 ? 1.f : 0.f);
    float wx1 = tx * (x0 < GD - 1 ? 1.f : 0.f);
    float wy0 = (1.f - ty) * (y0 >= 0 ? 1.f : 0.f);
    float wy1 = ty * (y0 < GD - 1 ? 1.f : 0.f);
    float wz0 = (1.f - tz) * (z0 >= 0 ? 1.f : 0.f);
    float wz1 = tz * (z0 < GD - 1 ? 1.f : 0.f);

    // x0 == -1: entry at xp=0 holds (v[0], v[1]); the needed x1-corner is the
    // LOW half. Fold into weight selects (wx0 is already 0 in that case).
    bool lo = (x0 < 0);
    cA = lo ? wx1 : wx0;
    cC = lo ? 0.f : wx1;

    int xb = xp << 3;
#define EIDX(zz, yy) \
    ((((zz) >> 2) << 14) + ((((yy) >> 1)) << 9) + xb + (((zz)&3) << 1) + ((yy)&1))
    e[0] = EIDX(zi0, yi0);
    e[1] = EIDX(zi0, yi1);
    e[2] = EIDX(zi1, yi0);
    e[3] = EIDX(zi1, yi1);
#undef EIDX
    w[0] = wz0 * wy0;
    w[1] = wz0 * wy1;
    w[2] = wz1 * wy0;
    w[3] = wz1 * wy1;
}

// Phase C: accumulate one gathered entry.
__device__ __forceinline__ void accum_corner(h8 h, float w, float cA, float cC,
                                             float& a0, float& a1, float& a2) {
    float eA = w * cA, eC = w * cC;
    a0 = fmaf(eA, (float)h[0], a0);
    a0 = fmaf(eC, (float)h[4], a0);
    a1 = fmaf(eA, (float)h[1], a1);
    a1 = fmaf(eC, (float)h[5], a1);
    a2 = fmaf(eA, (float)h[2], a2);
    a2 = fmaf(eC, (float)h[6], a2);
}

// ---------------------------------------------------------------------------
// Main kernel. Block = 256 threads = 1024 points = 768 float4.
// Coalesced nontemporal global I/O + LDS transpose; 16 gathers batched for MLP.
// ---------------------------------------------------------------------------
__global__ __launch_bounds__(256) void sample_bricks(const vfloat4* __restrict__ pts,
                                                     const h8* __restrict__ pg,
                                                     vfloat4* __restrict__ out,
                                                     int nf4) {
    __shared__ vfloat4 lds[768];
    int tid = threadIdx.x;
    int base = blockIdx.x * 768;

    vfloat4 v0 = {0.f, 0.f, 0.f, 0.f};
    vfloat4 v1 = {0.f, 0.f, 0.f, 0.f};
    vfloat4 v2 = {0.f, 0.f, 0.f, 0.f};
    if (base + tid < nf4) v0 = __builtin_nontemporal_load(&pts[base + tid]);
    if (base + 256 + tid < nf4) v1 = __builtin_nontemporal_load(&pts[base + 256 + tid]);
    if (base + 512 + tid < nf4) v2 = __builtin_nontemporal_load(&pts[base + 512 + tid]);
    lds[tid] = v0;
    lds[tid + 256] = v1;
    lds[tid + 512] = v2;
    __syncthreads();

    vfloat4 a = lds[tid * 3 + 0];
    vfloat4 b = lds[tid * 3 + 1];
    vfloat4 c = lds[tid * 3 + 2];
    float f[12] = {a.x, a.y, a.z, a.w, b.x, b.y, b.z, b.w, c.x, c.y, c.z, c.w};

    // Phase A: addresses + weights for all 4 points.
    int e[16];
    float w[16];
    float cA[4], cC[4];
#pragma unroll
    for (int p = 0; p < 4; ++p)
        prep_point(f[3 * p + 0], f[3 * p + 1], f[3 * p + 2], &e[4 * p], &w[4 * p],
                   cA[p], cC[p]);

    // Phase B: issue all 16 gathers (independent -> deep MLP).
    h8 h[16];
#pragma unroll
    for (int i = 0; i < 16; ++i) h[i] = pg[e[i]];

    // Phase C: FMA accumulation.
#pragma unroll
    for (int p = 0; p < 4; ++p) {
        float a0 = 0.f, a1 = 0.f, a2 = 0.f;
#pragma unroll
        for (int q = 0; q < 4; ++q)
            accum_corner(h[4 * p + q], w[4 * p + q], cA[p], cC[p], a0, a1, a2);
        f[3 * p + 0] += a0;
        f[3 * p + 1] += a1;
        f[3 * p + 2] += a2;
    }

    a = (vfloat4){f[0], f[1], f[2], f[3]};
    b = (vfloat4){f[4], f[5], f[6], f[7]};
    c = (vfloat4){f[8], f[9], f[10], f[11]};

    __syncthreads();
    lds[tid * 3 + 0] = a;
    lds[tid * 3 + 1] = b;
    lds[tid * 3 + 2] = c;
    __syncthreads();

    if (base + tid < nf4) __builtin_nontemporal_store(lds[tid], &out[base + tid]);
    if (base + 256 + tid < nf4)
        __builtin_nontemporal_store(lds[tid + 256], &out[base + 256 + tid]);
    if (base + 512 + tid < nf4)
        __builtin_nontemporal_store(lds[tid + 512], &out[base + 512 + tid]);
}

// ---------------------------------------------------------------------------
// Fallback (ws too small): direct 3-plane fp32 gather.
// ---------------------------------------------------------------------------
__device__ __forceinline__ void samp_add_direct(const float* __restrict__ g,
                                                float& px, float& py, float& pz) {
    float ix = fmaf(px, 32.f, 31.5f);
    float iy = fmaf(py, 32.f, 31.5f);
    float iz = fmaf(pz, 32.f, 31.5f);
    float fx = floorf(ix), fy = floorf(iy), fz = floorf(iz);
    float tx = ix - fx, ty = iy - fy, tz = iz - fz;
    int x0 = (int)fx, y0 = (int)fy, z0 = (int)fz;
    int xi0 = max(x0, 0), xi1 = min(x0 + 1, GD - 1);
    int yi0 = max(y0, 0), yi1 = min(y0 + 1, GD - 1);
    int zi0 = max(z0, 0), zi1 = min(z0 + 1, GD - 1);
    float wx0 = (1.f - tx) * (x0 >= 0 ? 1.f : 0.f);
    float wx1 = tx * (x0 < GD - 1 ? 1.f : 0.f);
    float wy0 = (1.f - ty) * (y0 >= 0 ? 1.f : 0.f);
    float wy1 = ty * (y0 < GD - 1 ? 1.f : 0.f);
    float wz0 = (1.f - tz) * (z0 >= 0 ? 1.f : 0.f);
    float wz1 = tz * (z0 < GD - 1 ? 1.f : 0.f);
    int zb0 = zi0 << 12, zb1 = zi1 << 12;
    int yb0 = yi0 << 6, yb1 = yi1 << 6;
    float wz0y0 = wz0 * wy0, wz0y1 = wz0 * wy1;
    float wz1y0 = wz1 * wy0, wz1y1 = wz1 * wy1;
    float s0 = 0.f, s1 = 0.f, s2 = 0.f;
#define CORNERD(zb, yb, xi, wgt)                 \
    {                                            \
        int idx = (zb) + (yb) + (xi);            \
        s0 = fmaf((wgt), g[idx], s0);            \
        s1 = fmaf((wgt), g[idx + GVOX], s1);     \
        s2 = fmaf((wgt), g[idx + 2 * GVOX], s2); \
    }
    CORNERD(zb0, yb0, xi0, wz0y0 * wx0);
    CORNERD(zb0, yb0, xi1, wz0y0 * wx1);
    CORNERD(zb0, yb1, xi0, wz0y1 * wx0);
    CORNERD(zb0, yb1, xi1, wz0y1 * wx1);
    CORNERD(zb1, yb0, xi0, wz1y0 * wx0);
    CORNERD(zb1, yb0, xi1, wz1y0 * wx1);
    CORNERD(zb1, yb1, xi0, wz1y1 * wx0);
    CORNERD(zb1, yb1, xi1, wz1y1 * wx1);
#undef CORNERD
    px += s0;
    py += s1;
    pz += s2;
}

__global__ __launch_bounds__(256) void sample_direct(const float* __restrict__ pts,
                                                     const float* __restrict__ g,
                                                     float* __restrict__ out, int npts) {
    int i = blockIdx.x * 256 + threadIdx.x;
    if (i >= npts) return;
    float x = pts[i * 3 + 0], y = pts[i * 3 + 1], z = pts[i * 3 + 2];
    samp_add_direct(g, x, y, z);
    out[i * 3 + 0] = x;
    out[i * 3 + 1] = y;
    out[i * 3 + 2] = z;
}

extern "C" void kernel_launch(void* const* d_in, const int* in_sizes, int n_in,
                              void* d_out, int out_size, void* d_ws, size_t ws_size,
                              hipStream_t stream) {
    const float* pts = (const float*)d_in[0];   // [B, N, 3] fp32
    const float* grid = (const float*)d_in[1];  // [3, 64, 64, 64] fp32

    int total_f = in_sizes[0];  // B*N*3
    int npts = total_f / 3;

    if (ws_size >= (size_t)GVOX * sizeof(h8) && (total_f % 4) == 0) {
        h8* pg = (h8*)d_ws;
        repack_bricks<<<(GVOX + 255) / 256, 256, 0, stream>>>(grid, pg);
        int nf4 = total_f / 4;            // float4 count
        int nblocks = (nf4 + 767) / 768;  // 768 float4 (1024 points) per block
        sample_bricks<<<nblocks, 256, 0, stream>>>((const vfloat4*)pts, pg,
                                                   (vfloat4*)d_out, nf4);
    } else {
        sample_direct<<<(npts + 255) / 256, 256, 0, stream>>>(pts, grid,
                                                              (float*)d_out, npts);
    }
}

// Round 4
// 93.383 us; speedup vs baseline: 1.8865x; 1.0098x over previous
//
#include <hip/hip_runtime.h>

#define GD 64
#define GVOX (GD * GD * GD)

typedef float vfloat4 __attribute__((ext_vector_type(4)));
typedef _Float16 h8 __attribute__((ext_vector_type(8)));

// ---------------------------------------------------------------------------
// Brick-tiled, x-pair-packed fp16 grid (4 MB in d_ws).
// Entry (z,y,x): channels of voxel (z,y,x) and (z,y,min(x+1,63)) as 8 fp16.
// One 128B cache line holds a (4z x 2y x 1x) brick:
//   E = (z>>2)<<14 | (y>>1)<<9 | x<<3 | (z&3)<<1 | (y&1)
// A point's 4 needed entries ({z0,z1} x {y0,y1}, same x) touch on average
// 1.875 lines instead of 4.
// ---------------------------------------------------------------------------
__global__ __launch_bounds__(256) void repack_bricks(const float* __restrict__ g,
                                                     h8* __restrict__ pg) {
    int t = blockIdx.x * 256 + threadIdx.x;
    if (t >= GVOX) return;
    int eo = t & 7;
    int x = (t >> 3) & 63;
    int by = (t >> 9) & 31;
    int bz = t >> 14;
    int z = (bz << 2) | (eo >> 1);
    int y = (by << 1) | (eo & 1);
    int v = (z << 12) | (y << 6) | x;
    int v1 = v + (x < GD - 1 ? 1 : 0);
    h8 o;
    o[0] = (_Float16)g[v];
    o[1] = (_Float16)g[v + GVOX];
    o[2] = (_Float16)g[v + 2 * GVOX];
    o[3] = (_Float16)0.f;
    o[4] = (_Float16)g[v1];
    o[5] = (_Float16)g[v1 + GVOX];
    o[6] = (_Float16)g[v1 + 2 * GVOX];
    o[7] = (_Float16)0.f;
    pg[t] = o;   // coalesced: consecutive t -> consecutive 16B
}

// ---------------------------------------------------------------------------
// Phase A: per-point address + weight computation (no loads).
// ---------------------------------------------------------------------------
__device__ __forceinline__ void prep_point(float px, float py, float pz,
                                           int* __restrict__ e, float* __restrict__ w,
                                           float& cA, float& cC) {
    // ix = ((x+1)*64 - 1) * 0.5 = 32*x + 31.5
    float ix = fmaf(px, 32.f, 31.5f);
    float iy = fmaf(py, 32.f, 31.5f);
    float iz = fmaf(pz, 32.f, 31.5f);
    float fx = floorf(ix), fy = floorf(iy), fz = floorf(iz);
    float tx = ix - fx, ty = iy - fy, tz = iz - fz;
    int x0 = (int)fx, y0 = (int)fy, z0 = (int)fz;

    int xp = min(max(x0, 0), GD - 1);
    int yi0 = max(y0, 0), yi1 = min(y0 + 1, GD - 1);
    int zi0 = max(z0, 0), zi1 = min(z0 + 1, GD - 1);

    float wx0 = (1.f - tx) * (x0 >= 0 ? 1.f : 0.f);
    float wx1 = tx * (x0 < GD - 1 ? 1.f : 0.f);
    float wy0 = (1.f - ty) * (y0 >= 0 ? 1.f : 0.f);
    float wy1 = ty * (y0 < GD - 1 ? 1.f : 0.f);
    float wz0 = (1.f - tz) * (z0 >= 0 ? 1.f : 0.f);
    float wz1 = tz * (z0 < GD - 1 ? 1.f : 0.f);

    // x0 == -1: entry at xp=0 holds (v[0], v[1]); the needed x1-corner is the
    // LOW half. Fold into 2 weight selects.
    bool lo = (x0 < 0);
    cA = lo ? wx1 : wx0;
    cC = lo ? 0.f : wx1;

    int xb = xp << 3;
#define EIDX(zz, yy) \
    ((((zz) >> 2) << 14) + ((((yy) >> 1)) << 9) + xb + (((zz)&3) << 1) + ((yy)&1))
    e[0] = EIDX(zi0, yi0);
    e[1] = EIDX(zi0, yi1);
    e[2] = EIDX(zi1, yi0);
    e[3] = EIDX(zi1, yi1);
#undef EIDX
    w[0] = wz0 * wy0;
    w[1] = wz0 * wy1;
    w[2] = wz1 * wy0;
    w[3] = wz1 * wy1;
}

// Phase C: accumulate one gathered entry.
__device__ __forceinline__ void accum_corner(h8 h, float w, float cA, float cC,
                                             float& a0, float& a1, float& a2) {
    float eA = w * cA, eC = w * cC;
    a0 = fmaf(eA, (float)h[0], a0);
    a0 = fmaf(eC, (float)h[4], a0);
    a1 = fmaf(eA, (float)h[1], a1);
    a1 = fmaf(eC, (float)h[5], a1);
    a2 = fmaf(eA, (float)h[2], a2);
    a2 = fmaf(eC, (float)h[6], a2);
}

// ---------------------------------------------------------------------------
// Main kernel. Block = 256 threads = 1024 points = 768 float4.
// Coalesced nontemporal global I/O + LDS transpose.
// sched_barrier(0) fences force all 16 gathers to stay in flight together
// (without them the scheduler re-serializes into load->use chains, VGPR=36).
// ---------------------------------------------------------------------------
__global__ __launch_bounds__(256) void sample_bricks(const vfloat4* __restrict__ pts,
                                                     const h8* __restrict__ pg,
                                                     vfloat4* __restrict__ out,
                                                     int nf4) {
    __shared__ vfloat4 lds[768];
    int tid = threadIdx.x;
    int base = blockIdx.x * 768;

    vfloat4 v0 = {0.f, 0.f, 0.f, 0.f};
    vfloat4 v1 = {0.f, 0.f, 0.f, 0.f};
    vfloat4 v2 = {0.f, 0.f, 0.f, 0.f};
    if (base + tid < nf4) v0 = __builtin_nontemporal_load(&pts[base + tid]);
    if (base + 256 + tid < nf4) v1 = __builtin_nontemporal_load(&pts[base + 256 + tid]);
    if (base + 512 + tid < nf4) v2 = __builtin_nontemporal_load(&pts[base + 512 + tid]);
    lds[tid] = v0;
    lds[tid + 256] = v1;
    lds[tid + 512] = v2;
    __syncthreads();

    vfloat4 a = lds[tid * 3 + 0];
    vfloat4 b = lds[tid * 3 + 1];
    vfloat4 c = lds[tid * 3 + 2];
    float f[12] = {a.x, a.y, a.z, a.w, b.x, b.y, b.z, b.w, c.x, c.y, c.z, c.w};

    // Phase A: addresses + weights for all 4 points.
    int e[16];
    float w[16];
    float cA[4], cC[4];
#pragma unroll
    for (int p = 0; p < 4; ++p)
        prep_point(f[3 * p + 0], f[3 * p + 1], f[3 * p + 2], &e[4 * p], &w[4 * p],
                   cA[p], cC[p]);

    // Phase B: issue ALL 16 gathers before any consumer (deep MLP).
    __builtin_amdgcn_sched_barrier(0);
    h8 h[16];
#pragma unroll
    for (int i = 0; i < 16; ++i) h[i] = pg[e[i]];
    __builtin_amdgcn_sched_barrier(0);

    // Phase C: FMA accumulation.
#pragma unroll
    for (int p = 0; p < 4; ++p) {
        float a0 = 0.f, a1 = 0.f, a2 = 0.f;
#pragma unroll
        for (int q = 0; q < 4; ++q)
            accum_corner(h[4 * p + q], w[4 * p + q], cA[p], cC[p], a0, a1, a2);
        f[3 * p + 0] += a0;
        f[3 * p + 1] += a1;
        f[3 * p + 2] += a2;
    }

    a = (vfloat4){f[0], f[1], f[2], f[3]};
    b = (vfloat4){f[4], f[5], f[6], f[7]};
    c = (vfloat4){f[8], f[9], f[10], f[11]};

    __syncthreads();
    lds[tid * 3 + 0] = a;
    lds[tid * 3 + 1] = b;
    lds[tid * 3 + 2] = c;
    __syncthreads();

    if (base + tid < nf4) __builtin_nontemporal_store(lds[tid], &out[base + tid]);
    if (base + 256 + tid < nf4)
        __builtin_nontemporal_store(lds[tid + 256], &out[base + 256 + tid]);
    if (base + 512 + tid < nf4)
        __builtin_nontemporal_store(lds[tid + 512], &out[base + 512 + tid]);
}

// ---------------------------------------------------------------------------
// Fallback (ws too small): direct 3-plane fp32 gather.
// ---------------------------------------------------------------------------
__device__ __forceinline__ void samp_add_direct(const float* __restrict__ g,
                                                float& px, float& py, float& pz) {
    float ix = fmaf(px, 32.f, 31.5f);
    float iy = fmaf(py, 32.f, 31.5f);
    float iz = fmaf(pz, 32.f, 31.5f);
    float fx = floorf(ix), fy = floorf(iy), fz = floorf(iz);
    float tx = ix - fx, ty = iy - fy, tz = iz - fz;
    int x0 = (int)fx, y0 = (int)fy, z0 = (int)fz;
    int xi0 = max(x0, 0), xi1 = min(x0 + 1, GD - 1);
    int yi0 = max(y0, 0), yi1 = min(y0 + 1, GD - 1);
    int zi0 = max(z0, 0), zi1 = min(z0 + 1, GD - 1);
    float wx0 = (1.f - tx) * (x0 >= 0 ? 1.f : 0.f);
    float wx1 = tx * (x0 < GD - 1 ? 1.f : 0.f);
    float wy0 = (1.f - ty) * (y0 >= 0 ? 1.f : 0.f);
    float wy1 = ty * (y0 < GD - 1 ? 1.f : 0.f);
    float wz0 = (1.f - tz) * (z0 >= 0 ? 1.f : 0.f);
    float wz1 = tz * (z0 < GD - 1 ? 1.f : 0.f);
    int zb0 = zi0 << 12, zb1 = zi1 << 12;
    int yb0 = yi0 << 6, yb1 = yi1 << 6;
    float wz0y0 = wz0 * wy0, wz0y1 = wz0 * wy1;
    float wz1y0 = wz1 * wy0, wz1y1 = wz1 * wy1;
    float s0 = 0.f, s1 = 0.f, s2 = 0.f;
#define CORNERD(zb, yb, xi, wgt)                 \
    {                                            \
        int idx = (zb) + (yb) + (xi);            \
        s0 = fmaf((wgt), g[idx], s0);            \
        s1 = fmaf((wgt), g[idx + GVOX], s1);     \
        s2 = fmaf((wgt), g[idx + 2 * GVOX], s2); \
    }
    CORNERD(zb0, yb0, xi0, wz0y0 * wx0);
    CORNERD(zb0, yb0, xi1, wz0y0 * wx1);
    CORNERD(zb0, yb1, xi0, wz0y1 * wx0);
    CORNERD(zb0, yb1, xi1, wz0y1 * wx1);
    CORNERD(zb1, yb0, xi0, wz1y0 * wx0);
    CORNERD(zb1, yb0, xi1, wz1y0 * wx1);
    CORNERD(zb1, yb1, xi0, wz1y1 * wx0);
    CORNERD(zb1, yb1, xi1, wz1y1 * wx1);
#undef CORNERD
    px += s0;
    py += s1;
    pz += s2;
}

__global__ __launch_bounds__(256) void sample_direct(const float* __restrict__ pts,
                                                     const float* __restrict__ g,
                                                     float* __restrict__ out, int npts) {
    int i = blockIdx.x * 256 + threadIdx.x;
    if (i >= npts) return;
    float x = pts[i * 3 + 0], y = pts[i * 3 + 1], z = pts[i * 3 + 2];
    samp_add_direct(g, x, y, z);
    out[i * 3 + 0] = x;
    out[i * 3 + 1] = y;
    out[i * 3 + 2] = z;
}

extern "C" void kernel_launch(void* const* d_in, const int* in_sizes, int n_in,
                              void* d_out, int out_size, void* d_ws, size_t ws_size,
                              hipStream_t stream) {
    const float* pts = (const float*)d_in[0];   // [B, N, 3] fp32
    const float* grid = (const float*)d_in[1];  // [3, 64, 64, 64] fp32

    int total_f = in_sizes[0];  // B*N*3
    int npts = total_f / 3;

    if (ws_size >= (size_t)GVOX * sizeof(h8) && (total_f % 4) == 0) {
        h8* pg = (h8*)d_ws;
        repack_bricks<<<(GVOX + 255) / 256, 256, 0, stream>>>(grid, pg);
        int nf4 = total_f / 4;            // float4 count
        int nblocks = (nf4 + 767) / 768;  // 768 float4 (1024 points) per block
        sample_bricks<<<nblocks, 256, 0, stream>>>((const vfloat4*)pts, pg,
                                                   (vfloat4*)d_out, nf4);
    } else {
        sample_direct<<<(npts + 255) / 256, 256, 0, stream>>>(pts, grid,
                                                              (float*)d_out, npts);
    }
}